// Round 1
// baseline (1242.577 us; speedup 1.0000x reference)
//
#include <hip/hip_runtime.h>

// ---------------- problem constants ----------------
// B=16384, FEAT=1024, FD=256, M=4 nodes, H1=4 heads x C1=128 (concat->512),
// H2=1 x C2=256 (mean), OUT=8.

#define GBK 16

__device__ __forceinline__ float sigmoidf_(float x) { return 1.0f / (1.0f + expf(-x)); }
__device__ __forceinline__ float gelu_(float x) {
    return 0.5f * x * (1.0f + erff(x * 0.70710678118654752440f));
}

// ---------------- fp32 NT GEMM: C[M,N] = A[M,K] * Bw[N,K]^T (+bias, +act) ----
// BM=BN=128, BK=16, 256 threads, 8x8 micro-tile per thread.
template<int ACT, bool HAS_BIAS>
__global__ __launch_bounds__(256)
void gemm_nt_f32(const float* __restrict__ A, const float* __restrict__ Bw,
                 const float* __restrict__ bias, float* __restrict__ C,
                 int K, int lda, int ldc)
{
    __shared__ float As[GBK][132];
    __shared__ float Bs[GBK][132];
    const int t  = threadIdx.x;
    const int tx = t & 15;          // 16 col groups
    const int ty = t >> 4;          // 16 row groups
    const int lr = t >> 2;          // 0..63 staging row
    const int lk = (t & 3) << 2;    // 0,4,8,12 staging k
    const long rowA = (long)blockIdx.y * 128;
    const long colB = (long)blockIdx.x * 128;
    const float* Ap  = A  + (rowA + lr) * (long)lda + lk;
    const float* Ap2 = Ap + 64L * lda;
    const float* Bp  = Bw + (colB + lr) * (long)K + lk;
    const float* Bp2 = Bp + 64L * K;

    float acc[8][8] = {};
    for (int k0 = 0; k0 < K; k0 += GBK) {
        float4 a0 = *(const float4*)(Ap  + k0);
        float4 a1 = *(const float4*)(Ap2 + k0);
        float4 b0 = *(const float4*)(Bp  + k0);
        float4 b1 = *(const float4*)(Bp2 + k0);
        if (k0) __syncthreads();
        As[lk+0][lr]    = a0.x; As[lk+1][lr]    = a0.y; As[lk+2][lr]    = a0.z; As[lk+3][lr]    = a0.w;
        As[lk+0][lr+64] = a1.x; As[lk+1][lr+64] = a1.y; As[lk+2][lr+64] = a1.z; As[lk+3][lr+64] = a1.w;
        Bs[lk+0][lr]    = b0.x; Bs[lk+1][lr]    = b0.y; Bs[lk+2][lr]    = b0.z; Bs[lk+3][lr]    = b0.w;
        Bs[lk+0][lr+64] = b1.x; Bs[lk+1][lr+64] = b1.y; Bs[lk+2][lr+64] = b1.z; Bs[lk+3][lr+64] = b1.w;
        __syncthreads();
        #pragma unroll
        for (int k = 0; k < GBK; ++k) {
            float4 av0 = *(const float4*)&As[k][ty*8];
            float4 av1 = *(const float4*)&As[k][ty*8+4];
            float4 bv0 = *(const float4*)&Bs[k][tx*8];
            float4 bv1 = *(const float4*)&Bs[k][tx*8+4];
            float a[8] = {av0.x,av0.y,av0.z,av0.w,av1.x,av1.y,av1.z,av1.w};
            float b[8] = {bv0.x,bv0.y,bv0.z,bv0.w,bv1.x,bv1.y,bv1.z,bv1.w};
            #pragma unroll
            for (int i = 0; i < 8; ++i)
                #pragma unroll
                for (int j = 0; j < 8; ++j)
                    acc[i][j] = fmaf(a[i], b[j], acc[i][j]);
        }
    }
    // epilogue
    float bj[8];
    #pragma unroll
    for (int j = 0; j < 8; ++j)
        bj[j] = HAS_BIAS ? bias[colB + tx*8 + j] : 0.0f;
    #pragma unroll
    for (int i = 0; i < 8; ++i) {
        const long row = rowA + ty*8 + i;
        float v[8];
        #pragma unroll
        for (int j = 0; j < 8; ++j) {
            float x = acc[i][j] + bj[j];
            if (ACT == 1) x = fmaxf(x, 0.0f);
            v[j] = x;
        }
        float* Cp = C + row * (long)ldc + colB + tx*8;
        *(float4*)(Cp)     = make_float4(v[0], v[1], v[2], v[3]);
        *(float4*)(Cp + 4) = make_float4(v[4], v[5], v[6], v[7]);
    }
}

// ---------------- GAT1 attention: one wave per (sample b, head h) -----------
// h1 layout [B,4,512]; head slice h*128.. ; in-place update (reads complete
// before stores; each (b,h) slice is owned by exactly one wave).
__global__ __launch_bounds__(256)
void gat1_attn_kernel(float* __restrict__ h1,
                      const int* __restrict__ missing,
                      const float* __restrict__ attl, const float* __restrict__ attr,
                      const float* __restrict__ bias)
{
    const int gtid = blockIdx.x * 256 + threadIdx.x;
    const int wid  = gtid >> 6;
    const int lane = threadIdx.x & 63;
    const int b = wid >> 2;
    const int h = wid & 3;
    const int cb = h * 128 + lane;          // c0 = lane, c1 = lane+64
    float* base = h1 + (size_t)b * 2048 + cb;

    float hr[4][2];
    #pragma unroll
    for (int j = 0; j < 4; ++j) { hr[j][0] = base[j*512]; hr[j][1] = base[j*512 + 64]; }
    const float al0 = attl[cb], al1 = attl[cb+64];
    const float ar0 = attr[cb], ar1 = attr[cb+64];

    // 16 logits + 4 al + 4 ar partial dot products, butterfly all-reduce
    float red[24];
    #pragma unroll
    for (int i = 0; i < 4; ++i)
        #pragma unroll
        for (int j = 0; j < 4; ++j)
            red[i*4+j] = hr[i][0]*hr[j][0] + hr[i][1]*hr[j][1];
    #pragma unroll
    for (int j = 0; j < 4; ++j) {
        red[16+j] = hr[j][0]*al0 + hr[j][1]*al1;
        red[20+j] = hr[j][0]*ar0 + hr[j][1]*ar1;
    }
    #pragma unroll
    for (int m = 1; m < 64; m <<= 1)
        #pragma unroll
        for (int r = 0; r < 24; ++r)
            red[r] += __shfl_xor(red[r], m, 64);

    const int miss = missing[b];
    bool pres[4];
    #pragma unroll
    for (int mm = 0; mm < 4; ++mm) pres[mm] = (miss != mm + 1);

    float attn[4][4];
    #pragma unroll
    for (int i = 0; i < 4; ++i) {
        float av[4]; float mx = -3.4e38f;
        #pragma unroll
        for (int j = 0; j < 4; ++j) {
            const bool mk = (i == j) || (pres[i] && pres[j]);
            float v = (red[20+i] + red[16+j]) * sigmoidf_(red[i*4+j]);
            v = (v >= 0.0f) ? v : 0.2f * v;     // leaky 0.2
            av[j] = mk ? v : -1e30f;
            mx = fmaxf(mx, av[j]);
        }
        float den = 0.0f;
        #pragma unroll
        for (int j = 0; j < 4; ++j) { av[j] = expf(av[j] - mx); den += av[j]; }
        const float inv = 1.0f / den;
        #pragma unroll
        for (int j = 0; j < 4; ++j) attn[i][j] = av[j] * inv;
    }

    const float b0 = bias[cb], b1 = bias[cb+64];
    #pragma unroll
    for (int i = 0; i < 4; ++i) {
        float o0 = b0, o1 = b1;
        #pragma unroll
        for (int j = 0; j < 4; ++j) { o0 += attn[i][j]*hr[j][0]; o1 += attn[i][j]*hr[j][1]; }
        base[i*512]      = gelu_(o0);
        base[i*512 + 64] = gelu_(o1);
    }
}

// ------- GAT2 attention + node-mean pool + LayerNorm: one wave per sample ----
// h2 layout [B,4,256]; writes normed [B,256].
__global__ __launch_bounds__(256)
void gat2_attn_kernel(const float* __restrict__ h2,
                      const int* __restrict__ missing,
                      const float* __restrict__ attl, const float* __restrict__ attr,
                      const float* __restrict__ bias,
                      const float* __restrict__ lng, const float* __restrict__ lnb,
                      float* __restrict__ normed)
{
    const int gtid = blockIdx.x * 256 + threadIdx.x;
    const int b = gtid >> 6;
    const int lane = threadIdx.x & 63;
    const float4* hp = (const float4*)(h2 + (size_t)b * 1024);

    float4 hr[4];
    #pragma unroll
    for (int j = 0; j < 4; ++j) hr[j] = hp[j*64 + lane];
    const float4 al = ((const float4*)attl)[lane];
    const float4 ar = ((const float4*)attr)[lane];

    float red[24];
    #pragma unroll
    for (int i = 0; i < 4; ++i)
        #pragma unroll
        for (int j = 0; j < 4; ++j)
            red[i*4+j] = hr[i].x*hr[j].x + hr[i].y*hr[j].y + hr[i].z*hr[j].z + hr[i].w*hr[j].w;
    #pragma unroll
    for (int j = 0; j < 4; ++j) {
        red[16+j] = hr[j].x*al.x + hr[j].y*al.y + hr[j].z*al.z + hr[j].w*al.w;
        red[20+j] = hr[j].x*ar.x + hr[j].y*ar.y + hr[j].z*ar.z + hr[j].w*ar.w;
    }
    #pragma unroll
    for (int m = 1; m < 64; m <<= 1)
        #pragma unroll
        for (int r = 0; r < 24; ++r)
            red[r] += __shfl_xor(red[r], m, 64);

    const int miss = missing[b];
    bool pres[4];
    #pragma unroll
    for (int mm = 0; mm < 4; ++mm) pres[mm] = (miss != mm + 1);

    float wsum[4] = {0.f, 0.f, 0.f, 0.f};   // 0.25 * sum_i attn[i][j]
    #pragma unroll
    for (int i = 0; i < 4; ++i) {
        float av[4]; float mx = -3.4e38f;
        #pragma unroll
        for (int j = 0; j < 4; ++j) {
            const bool mk = (i == j) || (pres[i] && pres[j]);
            float v = (red[20+i] + red[16+j]) * sigmoidf_(red[i*4+j]);
            v = (v >= 0.0f) ? v : 0.2f * v;
            av[j] = mk ? v : -1e30f;
            mx = fmaxf(mx, av[j]);
        }
        float den = 0.0f;
        #pragma unroll
        for (int j = 0; j < 4; ++j) { av[j] = expf(av[j] - mx); den += av[j]; }
        const float inv = 0.25f / den;
        #pragma unroll
        for (int j = 0; j < 4; ++j) wsum[j] += av[j] * inv;
    }

    const float4 bv = ((const float4*)bias)[lane];
    float pooled[4] = {bv.x, bv.y, bv.z, bv.w};
    #pragma unroll
    for (int j = 0; j < 4; ++j) {
        pooled[0] += wsum[j] * hr[j].x;
        pooled[1] += wsum[j] * hr[j].y;
        pooled[2] += wsum[j] * hr[j].z;
        pooled[3] += wsum[j] * hr[j].w;
    }

    float s1 = pooled[0] + pooled[1] + pooled[2] + pooled[3];
    float s2 = pooled[0]*pooled[0] + pooled[1]*pooled[1] + pooled[2]*pooled[2] + pooled[3]*pooled[3];
    #pragma unroll
    for (int m = 1; m < 64; m <<= 1) {
        s1 += __shfl_xor(s1, m, 64);
        s2 += __shfl_xor(s2, m, 64);
    }
    const float mu   = s1 * (1.0f / 256.0f);
    const float var  = s2 * (1.0f / 256.0f) - mu * mu;
    const float rstd = rsqrtf(var + 1e-5f);
    const float4 g  = ((const float4*)lng)[lane];
    const float4 bb = ((const float4*)lnb)[lane];
    float4 o;
    o.x = (pooled[0] - mu) * rstd * g.x + bb.x;
    o.y = (pooled[1] - mu) * rstd * g.y + bb.y;
    o.z = (pooled[2] - mu) * rstd * g.z + bb.z;
    o.w = (pooled[3] - mu) * rstd * g.w + bb.w;
    ((float4*)normed)[(size_t)b * 64 + lane] = o;
}

// ---------------- head2: out[b,o] = hid[b,:] . W2[o,:] + b2[o] --------------
__global__ __launch_bounds__(256)
void head2_kernel(const float* __restrict__ hid, const float* __restrict__ W2,
                  const float* __restrict__ b2, float* __restrict__ out)
{
    const int t = blockIdx.x * 256 + threadIdx.x;
    const int b = t >> 3, o = t & 7;
    const float4* hp = (const float4*)(hid + (size_t)b * 256);
    const float4* wp = (const float4*)(W2 + o * 256);
    float acc = b2[o];
    #pragma unroll 8
    for (int c = 0; c < 64; ++c) {
        const float4 hv = hp[c], wv = wp[c];
        acc += hv.x*wv.x + hv.y*wv.y + hv.z*wv.z + hv.w*wv.w;
    }
    out[t] = acc;
}

// ---------------- launch ----------------------------------------------------
extern "C" void kernel_launch(void* const* d_in, const int* in_sizes, int n_in,
                              void* d_out, int out_size, void* d_ws, size_t ws_size,
                              hipStream_t stream)
{
    (void)in_sizes; (void)n_in; (void)out_size; (void)ws_size;
    const float* X[4]  = {(const float*)d_in[0], (const float*)d_in[1],
                          (const float*)d_in[2], (const float*)d_in[3]};
    const int*   miss  = (const int*)d_in[4];
    const float* Wm[4] = {(const float*)d_in[5], (const float*)d_in[7],
                          (const float*)d_in[9], (const float*)d_in[11]};
    const float* bm[4] = {(const float*)d_in[6], (const float*)d_in[8],
                          (const float*)d_in[10], (const float*)d_in[12]};
    const float* g1_W  = (const float*)d_in[13];
    const float* g1_al = (const float*)d_in[14];
    const float* g1_ar = (const float*)d_in[15];
    const float* g1_b  = (const float*)d_in[16];
    const float* g2_W  = (const float*)d_in[17];
    const float* g2_al = (const float*)d_in[18];
    const float* g2_ar = (const float*)d_in[19];
    const float* g2_b  = (const float*)d_in[20];
    const float* ln_g  = (const float*)d_in[21];
    const float* ln_b  = (const float*)d_in[22];
    const float* h_W1  = (const float*)d_in[23];
    const float* h_b1  = (const float*)d_in[24];
    const float* h_W2  = (const float*)d_in[25];
    const float* h_b2  = (const float*)d_in[26];
    float* out = (float*)d_out;

    // workspace layout (fp32 elements):
    //  [0 .. 16777216)            feats [16384,1024]  (later reused as h2 [65536,256])
    //  [16777216 .. 50331648)     h1/x1 [65536,512]   (later reused: normed+hid)
    float* ws     = (float*)d_ws;
    float* feats  = ws;
    float* h1     = ws + 16777216;
    float* h2     = ws;                       // feats dead after gemm1
    float* normed = ws + 16777216;            // h1 dead after gemm2
    float* hid    = normed + 4194304;

    const dim3 blk(256);

    // 1) per-modality projections -> feats[B,4,256] (row stride 1024, col offset m*256)
    for (int m = 0; m < 4; ++m)
        gemm_nt_f32<0, true><<<dim3(2, 128), blk, 0, stream>>>(
            X[m], Wm[m], bm[m], feats + m * 256, /*K=*/1024, /*lda=*/1024, /*ldc=*/1024);

    // 2) gat1 linear: h1[65536,512] = feats[65536,256] @ g1_W^T (no bias)
    gemm_nt_f32<0, false><<<dim3(4, 512), blk, 0, stream>>>(
        feats, g1_W, nullptr, h1, 256, 256, 512);

    // 3) gat1 attention + bias + gelu (in-place on h1), one wave per (b,h)
    gat1_attn_kernel<<<dim3(16384), blk, 0, stream>>>(h1, miss, g1_al, g1_ar, g1_b);

    // 4) gat2 linear: h2[65536,256] = x1[65536,512] @ g2_W^T
    gemm_nt_f32<0, false><<<dim3(2, 512), blk, 0, stream>>>(
        h1, g2_W, nullptr, h2, 512, 512, 256);

    // 5) gat2 attention + pool + layernorm -> normed[16384,256], one wave per b
    gat2_attn_kernel<<<dim3(4096), blk, 0, stream>>>(
        h2, miss, g2_al, g2_ar, g2_b, ln_g, ln_b, normed);

    // 6) head1: hid = relu(normed @ h_W1^T + h_b1)
    gemm_nt_f32<1, true><<<dim3(2, 128), blk, 0, stream>>>(
        normed, h_W1, h_b1, hid, 256, 256, 256);

    // 7) head2: out[16384,8]
    head2_kernel<<<dim3(512), blk, 0, stream>>>(hid, h_W2, h_b2, out);
}

// Round 4
// 422.558 us; speedup vs baseline: 2.9406x; 2.9406x over previous
//
#include <hip/hip_runtime.h>

// ---------------- problem constants ----------------
// B=16384, FEAT=1024, FD=256, M=4 nodes, H1=4x128 (concat->512), H2=1x256, OUT=8.

typedef __attribute__((ext_vector_type(8))) _Float16 f16x8;
typedef __attribute__((ext_vector_type(4))) float f32x4;

struct P4 { const float* p[4]; };

__device__ __forceinline__ float sigmoidf_(float x) { return 1.0f / (1.0f + expf(-x)); }
__device__ __forceinline__ float gelu_(float x) {
    return 0.5f * x * (1.0f + erff(x * 0.70710678118654752440f));
}

// ---------------- fp16-MFMA NT GEMM: C[M,N] = act(A[M,K] @ Bw[N,K]^T + bias) -
// fp32 in memory, converted to fp16 during LDS staging; fp32 accumulate.
// BM=BN=128, BK=32, 256 threads = 4 waves (2x2), each wave owns 64x64 out.
// grid.z batches independent (A,W,bias) triples writing C + z*zofs.
template<int ACT, bool HAS_BIAS>
__global__ __launch_bounds__(256)
void gemm_nt_mfma(P4 A4, P4 W4, P4 b4, float* __restrict__ C,
                  int K, int lda, int ldc, int zofs)
{
    __shared__ __align__(16) _Float16 As[128][32];
    __shared__ __align__(16) _Float16 Bs[128][32];
    const int z = blockIdx.z;
    const float* __restrict__ A    = A4.p[z];
    const float* __restrict__ Bw   = W4.p[z];
    const float* __restrict__ bias = b4.p[z];
    float* __restrict__ Cz = C + (long)z * zofs;

    const int t    = threadIdx.x;
    const int lane = t & 63;
    const int w    = t >> 6;
    const int wr   = (w >> 1) << 6;     // wave row base (0/64)
    const int wc   = (w & 1) << 6;      // wave col base (0/64)
    const long rowA = (long)blockIdx.y * 128;
    const long colB = (long)blockIdx.x * 128;

    f32x4 acc[4][4] = {};

    for (int k0 = 0; k0 < K; k0 += 32) {
        // ---- stage 128x32 fp32 tiles of A and Bw, convert to fp16 ----
        float4 areg[4], breg[4];
        #pragma unroll
        for (int i = 0; i < 4; ++i) {
            const int f = t + i * 256;          // float4 slot 0..1023
            const int r = f >> 3;               // row 0..127
            const int c = (f & 7) << 2;         // col 0,4,..28
            areg[i] = *(const float4*)(A  + (rowA + r) * (long)lda + k0 + c);
            breg[i] = *(const float4*)(Bw + (colB + r) * (long)K   + k0 + c);
        }
        if (k0) __syncthreads();
        #pragma unroll
        for (int i = 0; i < 4; ++i) {
            const int f = t + i * 256;
            const int r = f >> 3;
            const int c = (f & 7) << 2;
            union { _Float16 h[4]; uint2 u; } pa, pb;
            pa.h[0] = (_Float16)areg[i].x; pa.h[1] = (_Float16)areg[i].y;
            pa.h[2] = (_Float16)areg[i].z; pa.h[3] = (_Float16)areg[i].w;
            pb.h[0] = (_Float16)breg[i].x; pb.h[1] = (_Float16)breg[i].y;
            pb.h[2] = (_Float16)breg[i].z; pb.h[3] = (_Float16)breg[i].w;
            *(uint2*)&As[r][c] = pa.u;
            *(uint2*)&Bs[r][c] = pb.u;
        }
        __syncthreads();

        // ---- fragments + MFMA ----
        const int fr = lane & 15;
        const int fg = (lane >> 4) << 3;
        f16x8 af[4], bf[4];
        #pragma unroll
        for (int m = 0; m < 4; ++m) af[m] = *(const f16x8*)&As[wr + m*16 + fr][fg];
        #pragma unroll
        for (int n = 0; n < 4; ++n) bf[n] = *(const f16x8*)&Bs[wc + n*16 + fr][fg];
        #pragma unroll
        for (int m = 0; m < 4; ++m)
            #pragma unroll
            for (int n = 0; n < 4; ++n)
                acc[m][n] = __builtin_amdgcn_mfma_f32_16x16x32_f16(af[m], bf[n], acc[m][n], 0, 0, 0);
        __syncthreads();
    }

    // ---- epilogue: C/D layout col = lane&15, row = (lane>>4)*4 + j ----
    const int fr = lane & 15;
    const int fq = lane >> 4;
    #pragma unroll
    for (int n = 0; n < 4; ++n) {
        const long col = colB + wc + n*16 + fr;
        const float bn = HAS_BIAS ? bias[col] : 0.0f;
        #pragma unroll
        for (int m = 0; m < 4; ++m) {
            const long row0 = rowA + wr + m*16 + fq*4;
            #pragma unroll
            for (int j = 0; j < 4; ++j) {
                float x = acc[m][n][j] + bn;
                if (ACT == 1) x = fmaxf(x, 0.0f);
                Cz[(row0 + j) * (long)ldc + col] = x;
            }
        }
    }
}

// ---------------- GAT1 attention: one wave per (sample b, head h) -----------
// h1 layout [B,4,512]; in-place (each (b,h) slice owned by exactly one wave).
__global__ __launch_bounds__(256)
void gat1_attn_kernel(float* __restrict__ h1,
                      const int* __restrict__ missing,
                      const float* __restrict__ attl, const float* __restrict__ attr,
                      const float* __restrict__ bias)
{
    const int gtid = blockIdx.x * 256 + threadIdx.x;
    const int wid  = gtid >> 6;
    const int lane = threadIdx.x & 63;
    const int b = wid >> 2;
    const int h = wid & 3;
    const int cb = h * 128 + lane;
    float* base = h1 + (size_t)b * 2048 + cb;

    float hr[4][2];
    #pragma unroll
    for (int j = 0; j < 4; ++j) { hr[j][0] = base[j*512]; hr[j][1] = base[j*512 + 64]; }
    const float al0 = attl[cb], al1 = attl[cb+64];
    const float ar0 = attr[cb], ar1 = attr[cb+64];

    float red[24];
    #pragma unroll
    for (int i = 0; i < 4; ++i)
        #pragma unroll
        for (int j = 0; j < 4; ++j)
            red[i*4+j] = hr[i][0]*hr[j][0] + hr[i][1]*hr[j][1];
    #pragma unroll
    for (int j = 0; j < 4; ++j) {
        red[16+j] = hr[j][0]*al0 + hr[j][1]*al1;
        red[20+j] = hr[j][0]*ar0 + hr[j][1]*ar1;
    }
    #pragma unroll
    for (int m = 1; m < 64; m <<= 1)
        #pragma unroll
        for (int r = 0; r < 24; ++r)
            red[r] += __shfl_xor(red[r], m, 64);

    const int miss = missing[b];
    bool pres[4];
    #pragma unroll
    for (int mm = 0; mm < 4; ++mm) pres[mm] = (miss != mm + 1);

    float attn[4][4];
    #pragma unroll
    for (int i = 0; i < 4; ++i) {
        float av[4]; float mx = -3.4e38f;
        #pragma unroll
        for (int j = 0; j < 4; ++j) {
            const bool mk = (i == j) || (pres[i] && pres[j]);
            float v = (red[20+i] + red[16+j]) * sigmoidf_(red[i*4+j]);
            v = (v >= 0.0f) ? v : 0.2f * v;
            av[j] = mk ? v : -1e30f;
            mx = fmaxf(mx, av[j]);
        }
        float den = 0.0f;
        #pragma unroll
        for (int j = 0; j < 4; ++j) { av[j] = expf(av[j] - mx); den += av[j]; }
        const float inv = 1.0f / den;
        #pragma unroll
        for (int j = 0; j < 4; ++j) attn[i][j] = av[j] * inv;
    }

    const float b0 = bias[cb], b1 = bias[cb+64];
    #pragma unroll
    for (int i = 0; i < 4; ++i) {
        float o0 = b0, o1 = b1;
        #pragma unroll
        for (int j = 0; j < 4; ++j) { o0 += attn[i][j]*hr[j][0]; o1 += attn[i][j]*hr[j][1]; }
        base[i*512]      = gelu_(o0);
        base[i*512 + 64] = gelu_(o1);
    }
}

// ------- GAT2 attention + node-mean pool + LayerNorm: one wave per sample ----
__global__ __launch_bounds__(256)
void gat2_attn_kernel(const float* __restrict__ h2,
                      const int* __restrict__ missing,
                      const float* __restrict__ attl, const float* __restrict__ attr,
                      const float* __restrict__ bias,
                      const float* __restrict__ lng, const float* __restrict__ lnb,
                      float* __restrict__ normed)
{
    const int gtid = blockIdx.x * 256 + threadIdx.x;
    const int b = gtid >> 6;
    const int lane = threadIdx.x & 63;
    const float4* hp = (const float4*)(h2 + (size_t)b * 1024);

    float4 hr[4];
    #pragma unroll
    for (int j = 0; j < 4; ++j) hr[j] = hp[j*64 + lane];
    const float4 al = ((const float4*)attl)[lane];
    const float4 ar = ((const float4*)attr)[lane];

    float red[24];
    #pragma unroll
    for (int i = 0; i < 4; ++i)
        #pragma unroll
        for (int j = 0; j < 4; ++j)
            red[i*4+j] = hr[i].x*hr[j].x + hr[i].y*hr[j].y + hr[i].z*hr[j].z + hr[i].w*hr[j].w;
    #pragma unroll
    for (int j = 0; j < 4; ++j) {
        red[16+j] = hr[j].x*al.x + hr[j].y*al.y + hr[j].z*al.z + hr[j].w*al.w;
        red[20+j] = hr[j].x*ar.x + hr[j].y*ar.y + hr[j].z*ar.z + hr[j].w*ar.w;
    }
    #pragma unroll
    for (int m = 1; m < 64; m <<= 1)
        #pragma unroll
        for (int r = 0; r < 24; ++r)
            red[r] += __shfl_xor(red[r], m, 64);

    const int miss = missing[b];
    bool pres[4];
    #pragma unroll
    for (int mm = 0; mm < 4; ++mm) pres[mm] = (miss != mm + 1);

    float wsum[4] = {0.f, 0.f, 0.f, 0.f};
    #pragma unroll
    for (int i = 0; i < 4; ++i) {
        float av[4]; float mx = -3.4e38f;
        #pragma unroll
        for (int j = 0; j < 4; ++j) {
            const bool mk = (i == j) || (pres[i] && pres[j]);
            float v = (red[20+i] + red[16+j]) * sigmoidf_(red[i*4+j]);
            v = (v >= 0.0f) ? v : 0.2f * v;
            av[j] = mk ? v : -1e30f;
            mx = fmaxf(mx, av[j]);
        }
        float den = 0.0f;
        #pragma unroll
        for (int j = 0; j < 4; ++j) { av[j] = expf(av[j] - mx); den += av[j]; }
        const float inv = 0.25f / den;
        #pragma unroll
        for (int j = 0; j < 4; ++j) wsum[j] += av[j] * inv;
    }

    const float4 bv = ((const float4*)bias)[lane];
    float pooled[4] = {bv.x, bv.y, bv.z, bv.w};
    #pragma unroll
    for (int j = 0; j < 4; ++j) {
        pooled[0] += wsum[j] * hr[j].x;
        pooled[1] += wsum[j] * hr[j].y;
        pooled[2] += wsum[j] * hr[j].z;
        pooled[3] += wsum[j] * hr[j].w;
    }

    float s1 = pooled[0] + pooled[1] + pooled[2] + pooled[3];
    float s2 = pooled[0]*pooled[0] + pooled[1]*pooled[1] + pooled[2]*pooled[2] + pooled[3]*pooled[3];
    #pragma unroll
    for (int m = 1; m < 64; m <<= 1) {
        s1 += __shfl_xor(s1, m, 64);
        s2 += __shfl_xor(s2, m, 64);
    }
    const float mu   = s1 * (1.0f / 256.0f);
    const float var  = s2 * (1.0f / 256.0f) - mu * mu;
    const float rstd = rsqrtf(var + 1e-5f);
    const float4 g  = ((const float4*)lng)[lane];
    const float4 bb = ((const float4*)lnb)[lane];
    float4 o;
    o.x = (pooled[0] - mu) * rstd * g.x + bb.x;
    o.y = (pooled[1] - mu) * rstd * g.y + bb.y;
    o.z = (pooled[2] - mu) * rstd * g.z + bb.z;
    o.w = (pooled[3] - mu) * rstd * g.w + bb.w;
    ((float4*)normed)[(size_t)b * 64 + lane] = o;
}

// ---------------- head2: out[b,o] = hid[b,:] . W2[o,:] + b2[o] --------------
__global__ __launch_bounds__(256)
void head2_kernel(const float* __restrict__ hid, const float* __restrict__ W2,
                  const float* __restrict__ b2, float* __restrict__ out)
{
    const int t = blockIdx.x * 256 + threadIdx.x;
    const int b = t >> 3, o = t & 7;
    const float4* hp = (const float4*)(hid + (size_t)b * 256);
    const float4* wp = (const float4*)(W2 + o * 256);
    float acc = b2[o];
    #pragma unroll 8
    for (int c = 0; c < 64; ++c) {
        const float4 hv = hp[c], wv = wp[c];
        acc += hv.x*wv.x + hv.y*wv.y + hv.z*wv.z + hv.w*wv.w;
    }
    out[t] = acc;
}

// ---------------- launch ----------------------------------------------------
extern "C" void kernel_launch(void* const* d_in, const int* in_sizes, int n_in,
                              void* d_out, int out_size, void* d_ws, size_t ws_size,
                              hipStream_t stream)
{
    (void)in_sizes; (void)n_in; (void)out_size; (void)ws_size;
    const float* X0 = (const float*)d_in[0];
    const float* X1 = (const float*)d_in[1];
    const float* X2 = (const float*)d_in[2];
    const float* X3 = (const float*)d_in[3];
    const int*   miss  = (const int*)d_in[4];
    const float* g1_W  = (const float*)d_in[13];
    const float* g1_al = (const float*)d_in[14];
    const float* g1_ar = (const float*)d_in[15];
    const float* g1_b  = (const float*)d_in[16];
    const float* g2_W  = (const float*)d_in[17];
    const float* g2_al = (const float*)d_in[18];
    const float* g2_ar = (const float*)d_in[19];
    const float* g2_b  = (const float*)d_in[20];
    const float* ln_g  = (const float*)d_in[21];
    const float* ln_b  = (const float*)d_in[22];
    const float* h_W1  = (const float*)d_in[23];
    const float* h_b1  = (const float*)d_in[24];
    const float* h_W2  = (const float*)d_in[25];
    const float* h_b2  = (const float*)d_in[26];
    float* out = (float*)d_out;

    // workspace (fp32 elems): feats [16384,1024] | h1 [65536,512];
    // feats reused as h2 [65536,256]; h1 reused as normed[16384,256]+hid[16384,256]
    float* ws     = (float*)d_ws;
    float* feats  = ws;
    float* h1     = ws + 16777216;
    float* h2     = ws;
    float* normed = ws + 16777216;
    float* hid    = normed + 4194304;

    const dim3 blk(256);

    P4 Xs  = {{X0, X1, X2, X3}};
    P4 Wms = {{(const float*)d_in[5], (const float*)d_in[7],
               (const float*)d_in[9], (const float*)d_in[11]}};
    P4 bms = {{(const float*)d_in[6], (const float*)d_in[8],
               (const float*)d_in[10], (const float*)d_in[12]}};
    P4 F4  = {{feats, feats, feats, feats}};
    P4 G1W = {{g1_W, g1_W, g1_W, g1_W}};
    P4 H14 = {{h1, h1, h1, h1}};
    P4 G2W = {{g2_W, g2_W, g2_W, g2_W}};
    P4 N4  = {{normed, normed, normed, normed}};
    P4 HW1 = {{h_W1, h_W1, h_W1, h_W1}};
    P4 HB1 = {{h_b1, h_b1, h_b1, h_b1}};
    P4 NUL = {{nullptr, nullptr, nullptr, nullptr}};

    // 1) per-modality projections (batched over z): feats[B,4,256]
    gemm_nt_mfma<0, true><<<dim3(2, 128, 4), blk, 0, stream>>>(
        Xs, Wms, bms, feats, /*K=*/1024, /*lda=*/1024, /*ldc=*/1024, /*zofs=*/256);

    // 2) gat1 linear: h1[65536,512] = feats[65536,256] @ g1_W^T
    gemm_nt_mfma<0, false><<<dim3(4, 512, 1), blk, 0, stream>>>(
        F4, G1W, NUL, h1, 256, 256, 512, 0);

    // 3) gat1 attention + bias + gelu (in-place on h1)
    gat1_attn_kernel<<<dim3(16384), blk, 0, stream>>>(h1, miss, g1_al, g1_ar, g1_b);

    // 4) gat2 linear: h2[65536,256] = x1[65536,512] @ g2_W^T
    gemm_nt_mfma<0, false><<<dim3(2, 512, 1), blk, 0, stream>>>(
        H14, G2W, NUL, h2, 512, 512, 256, 0);

    // 5) gat2 attention + pool + layernorm -> normed[16384,256]
    gat2_attn_kernel<<<dim3(4096), blk, 0, stream>>>(
        h2, miss, g2_al, g2_ar, g2_b, ln_g, ln_b, normed);

    // 6) head1: hid = relu(normed @ h_W1^T + h_b1)
    gemm_nt_mfma<1, true><<<dim3(2, 128, 1), blk, 0, stream>>>(
        N4, HW1, HB1, hid, 256, 256, 256, 0);

    // 7) head2: out[16384,8]
    head2_kernel<<<dim3(512), blk, 0, stream>>>(hid, h_W2, h_b2, out);
}